// Round 1
// baseline (721.612 us; speedup 1.0000x reference)
//
#include <hip/hip_runtime.h>
#include <hip/hip_cooperative_groups.h>
#include <math.h>

namespace cg = cooperative_groups;

#define TWO_G 19.6f   // 2*9.8, matches jnp's folded 2.0*G constant
#define NPART 256     // partial-sum rows (== grid size of the mid phase)

__device__ __forceinline__ float flow_q(float th, float d, float a) {
    // matches reference association: (theta * sqrt(2*G*h)) * area
    return th * sqrtf(TWO_G * d) * a;
}

__device__ __forceinline__ float wave_sum(float v) {
#pragma unroll
    for (int o = 32; o > 0; o >>= 1) v += __shfl_xor(v, o);
    return v;
}

// uniform-index broadcast without ds_bpermute latency (j is wave-uniform here)
__device__ __forceinline__ float lane_bcast(float v, int j) {
    return __int_as_float(__builtin_amdgcn_readlane(__float_as_int(v), j));
}

__device__ __forceinline__ void prefetch_row(const float2* __restrict__ S2,
                                             const float* __restrict__ th, int lane,
                                             float2 (&sv)[16], float (&tv)[16]) {
#pragma unroll
    for (int c = 0; c < 16; ++c) { sv[c] = S2[c * 64 + lane]; tv[c] = th[c * 64 + lane]; }
}

// serial spigot recurrence over 1024 spigots; nonzero q atomicAdd'ed into LDS acc.
// Identical arithmetic/order to the previous passing kernel.
__device__ __forceinline__ float solve_serial(float H, float inflow, int lane,
                                              float2 (&sv)[16], float (&tv)[16],
                                              float* acc) {
    float h0 = lane_bcast(sv[0].x, 0);
    float a0 = lane_bcast(sv[0].y, 0);
    float t0 = lane_bcast(tv[0], 0);
    float d0 = (H + inflow) - h0;
    float q0 = (d0 > 0.0f) ? flow_q(t0, d0, a0) : 0.0f;
    float cum = q0;
    float u   = H - 0.5f * cum;
    if (lane == 0 && q0 != 0.0f) atomicAdd(&acc[0], q0);

#pragma unroll
    for (int c = 0; c < 16; ++c) {
        float2 s = sv[c];
        unsigned long long avail = (c == 0) ? ~1ull : ~0ull;   // spigot 0 already done
        unsigned long long cand  = __ballot(s.x < u) & avail;
        float qmine = 0.0f;
        while (cand) {
            int j = __builtin_ctzll(cand);
            float hj = lane_bcast(s.x, j);
            float aj = lane_bcast(s.y, j);
            float tj = lane_bcast(tv[c], j);
            float d = u - hj;                    // > 0 by ballot
            float q = flow_q(tj, d, aj);
            cum += q;
            u = H - 0.5f * cum;
            if (lane == j) qmine = q;
            if (j >= 63) break;
            avail &= (~0ull << (j + 1));
            cand = __ballot(s.x < u) & avail;    // u decreased: subset of old cand
        }
        if (qmine != 0.0f) atomicAdd(&acc[c * 64 + lane], qmine);
    }
    return cum;
}

// ---- layer 0: single head bucket, 1024 spigots, one wave; dense q row -> P0 ----
__device__ __forceinline__ void layer0_body(const float* __restrict__ H0p,
                                            const float* __restrict__ S0,
                                            const float* __restrict__ theta0,
                                            const float* __restrict__ precip,
                                            float* __restrict__ out,
                                            float* __restrict__ P0, int lane) {
    const float H  = H0p[0];
    const float pl = precip[0] * 0.0625f;        // precip / 16 (exact)
    const float2* S2 = (const float2*)S0;
    float2 sv[16]; float tv[16];
#pragma unroll
    for (int c = 0; c < 16; ++c) { sv[c] = S2[c * 64 + lane]; tv[c] = theta0[c * 64 + lane]; }

    float h0 = lane_bcast(sv[0].x, 0);
    float a0 = lane_bcast(sv[0].y, 0);
    float t0 = lane_bcast(tv[0], 0);
    float d0 = (H + pl) - h0;
    float q0 = (d0 > 0.0f) ? flow_q(t0, d0, a0) : 0.0f;
    float cum = q0;
    float u   = H - 0.5f * cum;
    if (lane == 0) P0[0] = q0;

#pragma unroll
    for (int c = 0; c < 16; ++c) {
        int i = c * 64 + lane;
        float2 s = sv[c];
        unsigned long long avail = (c == 0) ? ~1ull : ~0ull;
        unsigned long long cand  = __ballot(s.x < u) & avail;
        float qmine = 0.0f;
        while (cand) {
            int j = __builtin_ctzll(cand);
            float hj = lane_bcast(s.x, j);
            float aj = lane_bcast(s.y, j);
            float tj = lane_bcast(tv[c], j);
            float d = u - hj;
            float q = flow_q(tj, d, aj);
            cum += q;
            u = H - 0.5f * cum;
            if (lane == j) qmine = q;
            if (j >= 63) break;
            avail &= (~0ull << (j + 1));
            cand = __ballot(s.x < u) & avail;
        }
        if (i > 0) P0[i] = qmine;
    }
    if (lane == 0) out[0] = (H - cum) + pl;      // H0_new
}

// ---- one mid layer inside the persistent kernel --------------------------------
__device__ __forceinline__ void mid_step(int l, int b, int lane, int tid, int bid,
                                         const float* __restrict__ Hmid, float pb,
                                         float2 (&sv)[16], float (&tv)[16],
                                         float2 (&svn)[16], float (&tvn)[16],
                                         const float2* __restrict__ Sn,
                                         const float* __restrict__ thn, bool doPrefetch,
                                         const float* __restrict__ Pin, bool firstLayer,
                                         float* __restrict__ Pout, float* __restrict__ out,
                                         float* acc, cg::grid_group& grid) {
    // 1) inflow partial gather FIRST (its waitcnt then retires before the prefetch
    //    loads -- vmcnt retires in issue order, so the serial phase isn't delayed
    //    by next-layer HBM traffic)
    float part = 0.0f;
    if (firstLayer) {
        if (lane == 0) part = Pin[b];            // q0 row, single partial (old npart=1)
    } else {
#pragma unroll
        for (int k = 0; k < 4; ++k) part += Pin[(size_t)(k * 64 + lane) * 1024 + b];
    }
    // 2) issue next layer's S/theta register prefetch: overlaps serial solve + sync
    if (doPrefetch) prefetch_row(Sn, thn, lane, svn, tvn);

    // 3) reduce, serial solve, outputs
    const float H      = Hmid[(size_t)l * 1024 + b];
    const float inflow = pb + wave_sum(part);
    const float cum    = solve_serial(H, inflow, lane, sv, tv, acc);
    if (lane == 0) out[1 + (size_t)l * 1024 + b] = (H - cum) + inflow;

    __syncthreads();
#pragma unroll
    for (int r = 0; r < 4; ++r) {
        const int idx = r * 256 + tid;
        Pout[(size_t)bid * 1024 + idx] = acc[idx];
        acc[idx] = 0.0f;                          // re-arm LDS for next layer
    }
    grid.sync();                                  // release partials / acquire for gather
}

// ---- the whole cascade: 1 cooperative kernel, 256 blocks (1/CU), 15 grid syncs --
__global__ __launch_bounds__(256, 1)
void cascade_kernel(const float* __restrict__ H0p, const float* __restrict__ Hmid,
                    const float* __restrict__ Hlast, const float* __restrict__ S0,
                    const float* __restrict__ Smid, const float* __restrict__ Slast,
                    const float* __restrict__ th0, const float* __restrict__ thmid,
                    const float* __restrict__ thlast, const float* __restrict__ precip,
                    float* __restrict__ out, float* __restrict__ PA, float* __restrict__ PB)
{
    cg::grid_group grid = cg::this_grid();
    __shared__ float acc[1024];
    const int tid  = threadIdx.x;
    const int lane = tid & 63;
    const int bid  = blockIdx.x;
    const int b    = bid * 4 + (tid >> 6);        // same bucket<->block grouping as before

#pragma unroll
    for (int r = 0; r < 4; ++r) acc[r * 256 + tid] = 0.0f;

    const float pb = precip[0] * (0.0625f / 1024.0f);   // exact: 2^-14 * precip
    const float2* S2m = (const float2*)Smid;

    float2 svA[16]; float tvA[16];                // register double-buffer for S/theta rows
    float2 svB[16]; float tvB[16];

    // prefetch mid layer 0 row for this wave's bucket
    prefetch_row(S2m + (size_t)b * 1024, thmid + (size_t)b * 1024, lane, svA, tvA);

    // head bucket on block 0 / wave 0 while everyone else streams layer-0 rows
    if (bid == 0 && tid < 64)
        layer0_body(H0p, S0, th0, precip, out, PA, lane);

    grid.sync();

#pragma unroll 1
    for (int l = 0; l < 14; l += 2) {
        // even layer: regs A, partials PA -> PB, prefetch l+1 into B
        mid_step(l, b, lane, tid, bid, Hmid, pb, svA, tvA, svB, tvB,
                 S2m + ((size_t)(l + 1) * 1024 * 1024 + (size_t)b * 1024),
                 thmid + ((size_t)(l + 1) * 1024 * 1024 + (size_t)b * 1024),
                 true, PA, l == 0, PB, out, acc, grid);
        // odd layer: regs B, partials PB -> PA, prefetch l+2 into A (if it exists)
        const bool  pf  = (l + 2) < 14;
        const size_t off = pf ? ((size_t)(l + 2) * 1024 * 1024 + (size_t)b * 1024)
                              : ((size_t)b * 1024);          // dummy valid ptr when !pf
        mid_step(l + 1, b, lane, tid, bid, Hmid, pb, svB, tvB, svA, tvA,
                 S2m + off, thmid + off, pf, PB, false, PA, out, acc, grid);
    }

    // last layer: 1 spigot per bucket; l=13 wrote PA
    {
        float part = 0.0f;
#pragma unroll
        for (int k = 0; k < 4; ++k) part += PA[(size_t)(k * 64 + lane) * 1024 + b];
        const float inflow = pb + wave_sum(part);
        if (lane == 0) {
            const float  Hv = Hlast[b];
            const float2 s  = ((const float2*)Slast)[b];
            const float  d  = (Hv + inflow) - s.x;
            const float  q  = (d > 0.0f) ? flow_q(thlast[b], d, s.y) : 0.0f;
            out[1 + 14 * 1024 + b]        = (Hv - q) + inflow;   // H_last_new
            out[1 + 14 * 1024 + 1024 + b] = q;                   // q_last
        }
    }
}

// ================= fallback: previous 16-kernel pipeline (unchanged numerics) ====
__global__ __launch_bounds__(64)
void layer0_kernel(const float* __restrict__ H0p, const float* __restrict__ S0,
                   const float* __restrict__ theta0, const float* __restrict__ precip,
                   float* __restrict__ out, float* __restrict__ P0)
{
    layer0_body(H0p, S0, theta0, precip, out, P0, threadIdx.x);
}

__global__ __launch_bounds__(256)
void mid_kernel(const float* __restrict__ Hl, const float* __restrict__ Sl,
                const float* __restrict__ thl, const float* __restrict__ Pin,
                int npart, float* __restrict__ Pout, float* __restrict__ outl,
                const float* __restrict__ precip)
{
    __shared__ float acc[1024];
    const int tid  = threadIdx.x;
    const int lane = tid & 63;
    const int b    = blockIdx.x * 4 + (tid >> 6);

#pragma unroll
    for (int r = 0; r < 4; ++r) acc[r * 256 + tid] = 0.0f;
    __syncthreads();

    const float pb = precip[0] * (0.0625f / 1024.0f);

    float part = 0.0f;
    for (int k = lane; k < npart; k += 64) part += Pin[(size_t)k * 1024 + b];

    float2 sv[16]; float tv[16];
    prefetch_row((const float2*)Sl + (size_t)b * 1024, thl + (size_t)b * 1024, lane, sv, tv);

    const float H      = Hl[b];
    const float inflow = pb + wave_sum(part);
    const float cum    = solve_serial(H, inflow, lane, sv, tv, acc);
    if (lane == 0) outl[b] = (H - cum) + inflow;

    __syncthreads();
#pragma unroll
    for (int r = 0; r < 4; ++r)
        Pout[(size_t)blockIdx.x * 1024 + r * 256 + tid] = acc[r * 256 + tid];
}

__global__ __launch_bounds__(256)
void last_kernel(const float* __restrict__ Hlast, const float* __restrict__ Slast,
                 const float* __restrict__ thlast, const float* __restrict__ Pin,
                 const float* __restrict__ precip, float* __restrict__ out)
{
    const int lane = threadIdx.x & 63;
    const int b    = blockIdx.x * 4 + (threadIdx.x >> 6);
    const float pb = precip[0] * (0.0625f / 1024.0f);

    float part = 0.0f;
#pragma unroll
    for (int k = 0; k < NPART / 64; ++k) part += Pin[(size_t)(k * 64 + lane) * 1024 + b];
    float inflow = pb + wave_sum(part);

    if (lane == 0) {
        float H = Hlast[b];
        float2 s = ((const float2*)Slast)[b];
        float d = (H + inflow) - s.x;
        float q = (d > 0.0f) ? flow_q(thlast[b], d, s.y) : 0.0f;
        out[1 + 14 * 1024 + b]        = (H - q) + inflow;
        out[1 + 14 * 1024 + 1024 + b] = q;
    }
}

extern "C" void kernel_launch(void* const* d_in, const int* in_sizes, int n_in,
                              void* d_out, int out_size, void* d_ws, size_t ws_size,
                              hipStream_t stream)
{
    (void)in_sizes; (void)n_in; (void)out_size; (void)ws_size;
    const float* H0     = (const float*)d_in[0];
    const float* Hmid   = (const float*)d_in[1];
    const float* Hlast  = (const float*)d_in[2];
    const float* S0     = (const float*)d_in[3];
    const float* Smid   = (const float*)d_in[4];
    const float* Slast  = (const float*)d_in[5];
    const float* th0    = (const float*)d_in[6];
    const float* thmid  = (const float*)d_in[7];
    const float* thlast = (const float*)d_in[8];
    const float* precip = (const float*)d_in[9];
    float* out = (float*)d_out;
    float* PA  = (float*)d_ws;                 // NPART x 1024 partials (ping)
    float* PB  = PA + (size_t)NPART * 1024;    // pong

    void* args[] = { &H0, &Hmid, &Hlast, &S0, &Smid, &Slast,
                     &th0, &thmid, &thlast, &precip, &out, &PA, &PB };
    hipError_t err = hipLaunchCooperativeKernel((const void*)cascade_kernel,
                                                dim3(256), dim3(256), args, 0, stream);
    if (err != hipSuccess) {
        // cooperative launch unavailable under capture -> previous best pipeline
        layer0_kernel<<<1, 64, 0, stream>>>(H0, S0, th0, precip, out, PA);
        float* cur = PA; float* nxt = PB; int npart = 1;
        for (int l = 0; l < 14; ++l) {
            mid_kernel<<<256, 256, 0, stream>>>(Hmid + (size_t)l * 1024,
                                                Smid + (size_t)l * 1024 * 1024 * 2,
                                                thmid + (size_t)l * 1024 * 1024,
                                                cur, npart, nxt,
                                                out + 1 + (size_t)l * 1024, precip);
            float* t = cur; cur = nxt; nxt = t; npart = NPART;
        }
        last_kernel<<<256, 256, 0, stream>>>(Hlast, Slast, thlast, cur, precip, out);
    }
}